// Round 9
// baseline (184.498 us; speedup 1.0000x reference)
//
#include <hip/hip_runtime.h>
#include <stdint.h>

#define TABLE_BITS 21
#define TABLE_SIZE (1u << TABLE_BITS)      // 2,097,152 entries > max key 1,999,999
#define TABLE_MASK (TABLE_SIZE - 1u)
#define BLOCK 256
#define EPT 4
#define CHUNK (BLOCK * EPT)                // 1024 elements/block (flags/out)
#define EPT2 16
#define CHUNK2 (BLOCK * EPT2)              // 4096 elements/block (hist/scatter)
#define RANK_BIT 0x40000000
#define RANK_MASK 0x3FFFFFFF
#define NB 256                             // key-range buckets
#define BSHIFT (TABLE_BITS - 8)            // 8192 keys per bucket
#define KPB (1 << BSHIFT)
#define KLOW_MASK (KPB - 1)
#define INF_PAT 0x7f7f7f7f
#define BJ_INVALID 0xFFFFFFFFu
#define IDS_SPLIT 4                        // blocks per bucket in k_ids

// ---- block exclusive scan (NT threads) ----
template<int NT>
__device__ __forceinline__ int blk_excl_scan(int v, int tid, int* total) {
    constexpr int NW = NT / 64;
    int lane = tid & 63, w = tid >> 6;
    int inc = v;
    #pragma unroll
    for (int off = 1; off < 64; off <<= 1) {
        int u = __shfl_up(inc, off, 64);
        if (lane >= off) inc += u;
    }
    __shared__ int part[NW];
    if (lane == 63) part[w] = inc;
    __syncthreads();
    if (tid < NW) {
        int p = part[tid];
        #pragma unroll
        for (int off = 1; off < NW; off <<= 1) {
            int u = __shfl_up(p, off, 64);
            if (tid >= off) p += u;
        }
        part[tid] = p;
    }
    __syncthreads();
    int excl = ((w == 0) ? 0 : part[w - 1]) + inc - v;
    int tot = part[NW - 1];
    __syncthreads();
    if (total) *total = tot;
    return excl;
}

// ---------- A: per-block 256-bucket histogram (LDS atomics only) ----------
__global__ __launch_bounds__(BLOCK) void k_hist(const int* __restrict__ x, int n,
                                                unsigned* __restrict__ hist) {
    __shared__ unsigned cnt[NB];
    int tid = threadIdx.x;
    cnt[tid] = 0;
    __syncthreads();
    int e0 = blockIdx.x * CHUNK2;
    #pragma unroll
    for (int k = 0; k < EPT2 / 4; ++k) {
        int idx = e0 + k * (BLOCK * 4) + tid * 4;
        if (idx + 4 <= n) {
            int4 v = *reinterpret_cast<const int4*>(x + idx);
            atomicAdd(&cnt[((unsigned)v.x & TABLE_MASK) >> BSHIFT], 1u);
            atomicAdd(&cnt[((unsigned)v.y & TABLE_MASK) >> BSHIFT], 1u);
            atomicAdd(&cnt[((unsigned)v.z & TABLE_MASK) >> BSHIFT], 1u);
            atomicAdd(&cnt[((unsigned)v.w & TABLE_MASK) >> BSHIFT], 1u);
        } else {
            for (int i = idx; i < n; ++i)
                atomicAdd(&cnt[((unsigned)x[i] & TABLE_MASK) >> BSHIFT], 1u);
        }
    }
    __syncthreads();
    hist[(size_t)blockIdx.x * NB + tid] = cnt[tid];
}

// ---------- B: per-bucket exclusive scan over blocks (in place) ----------
__global__ __launch_bounds__(256) void k_colscan(unsigned* __restrict__ hist, int SB2,
                                                 unsigned* __restrict__ bucketTot) {
    int j = blockIdx.x, tid = threadIdx.x;
    unsigned carry = 0;
    for (int b0 = 0; b0 < SB2; b0 += 256) {
        int b = b0 + tid;
        int v = (b < SB2) ? (int)hist[(size_t)b * NB + j] : 0;
        int tot;
        int excl = blk_excl_scan<256>(v, tid, &tot);
        if (b < SB2) hist[(size_t)b * NB + j] = carry + (unsigned)excl;
        carry += (unsigned)tot;
    }
    if (tid == 0) bucketTot[j] = carry;
}

// ---------- B2: exclusive scan of bucket totals ----------
__global__ __launch_bounds__(256) void k_bucketbase(const unsigned* __restrict__ bucketTot,
                                                    unsigned* __restrict__ bucketBase) {
    int tid = threadIdx.x;
    int v = (int)bucketTot[tid];
    int tot;
    int excl = blk_excl_scan<256>(v, tid, &tot);
    bucketBase[tid] = (unsigned)excl;
    if (tid == 255) bucketBase[256] = (unsigned)(excl + v);
}

// ---------- C: LDS-staged scatter -> split 6B pairs grouped by bucket ----------
__global__ __launch_bounds__(BLOCK) void k_scatter(const int* __restrict__ x, int n,
                                                   const unsigned* __restrict__ hist,
                                                   const unsigned* __restrict__ bucketBase,
                                                   unsigned* __restrict__ posArr,
                                                   unsigned short* __restrict__ klArr) {
    __shared__ unsigned cnt[NB];
    __shared__ unsigned lbase[NB + 1];
    __shared__ unsigned sbase[NB];
    __shared__ unsigned lpos[CHUNK2];              // 16 KB
    __shared__ unsigned short lkl[CHUNK2];         // 8 KB
    int tid = threadIdx.x;
    cnt[tid] = 0;
    sbase[tid] = bucketBase[tid] + hist[(size_t)blockIdx.x * NB + tid];
    __syncthreads();

    unsigned bjs[EPT2], kls[EPT2], los[EPT2];
    int e0 = blockIdx.x * CHUNK2;
    // pass 1: bucket ids + local offsets
    #pragma unroll
    for (int k = 0; k < EPT2 / 4; ++k) {
        int idx = e0 + k * (BLOCK * 4) + tid * 4;
        if (idx + 4 <= n) {
            int4 v = *reinterpret_cast<const int4*>(x + idx);
            unsigned kk[4] = {(unsigned)v.x & TABLE_MASK, (unsigned)v.y & TABLE_MASK,
                              (unsigned)v.z & TABLE_MASK, (unsigned)v.w & TABLE_MASK};
            #pragma unroll
            for (int j = 0; j < 4; ++j) {
                int e = k * 4 + j;
                bjs[e] = kk[j] >> BSHIFT;
                kls[e] = kk[j] & KLOW_MASK;
                los[e] = atomicAdd(&cnt[bjs[e]], 1u);
            }
        } else {
            #pragma unroll
            for (int j = 0; j < 4; ++j) {
                int e = k * 4 + j;
                int i = idx + j;
                if (i < n) {
                    unsigned kv = (unsigned)x[i] & TABLE_MASK;
                    bjs[e] = kv >> BSHIFT;
                    kls[e] = kv & KLOW_MASK;
                    los[e] = atomicAdd(&cnt[bjs[e]], 1u);
                } else {
                    bjs[e] = BJ_INVALID;
                }
            }
        }
    }
    __syncthreads();
    // scan local counts -> local bucket bases
    {
        int v = (int)cnt[tid];
        int tot;
        int ex = blk_excl_scan<256>(v, tid, &tot);
        lbase[tid] = (unsigned)ex;
        if (tid == 255) lbase[256] = (unsigned)(ex + v);
    }
    __syncthreads();
    // pass 2: place into LDS ordered by bucket
    #pragma unroll
    for (int k = 0; k < EPT2 / 4; ++k) {
        #pragma unroll
        for (int j = 0; j < 4; ++j) {
            int e = k * 4 + j;
            if (bjs[e] != BJ_INVALID) {
                unsigned dst = lbase[bjs[e]] + los[e];
                lpos[dst] = (unsigned)(e0 + k * (BLOCK * 4) + tid * 4 + j);
                lkl[dst]  = (unsigned short)kls[e];
            }
        }
    }
    __syncthreads();
    // flush: wave per bucket, contiguous bursts
    int wv = tid >> 6, ln = tid & 63;
    for (int j = wv; j < NB; j += BLOCK / 64) {
        unsigned ls = lbase[j], len = lbase[j + 1] - ls, gs = sbase[j];
        for (unsigned i = ln; i < len; i += 64) {
            posArr[gs + i] = lpos[ls + i];
            klArr[gs + i]  = lkl[ls + i];
        }
    }
}

// ---------- D: per-bucket first-idx in LDS; coalesced table write + flag bytes ----------
__global__ __launch_bounds__(512) void k_bucket_min(const unsigned* __restrict__ posArr,
                                                    const unsigned short* __restrict__ klArr,
                                                    const unsigned* __restrict__ bucketBase,
                                                    int* __restrict__ table,
                                                    unsigned char* __restrict__ flag) {
    __shared__ int fi[KPB];                 // 32 KB
    int j = blockIdx.x, tid = threadIdx.x;
    for (int k = tid; k < KPB; k += 512) fi[k] = INF_PAT;
    __syncthreads();
    unsigned s = bucketBase[j], e = bucketBase[j + 1];
    for (unsigned idx = s + tid; idx < e; idx += 512)
        atomicMin(&fi[klArr[idx]], (int)posArr[idx]);
    __syncthreads();
    int* dst = table + (size_t)j * KPB;
    for (int k = tid; k < KPB; k += 512) dst[k] = fi[k];
    // flag bytes: every position written exactly once (L2-hot re-read)
    for (unsigned idx = s + tid; idx < e; idx += 512) {
        unsigned pos = posArr[idx];
        flag[pos] = (unsigned char)(fi[klArr[idx]] == (int)pos);
    }
}

// ---------- E: flag bytes -> consecutive-bit per-block bitmask + blockSums ----------
__global__ __launch_bounds__(BLOCK) void k_flags(const unsigned char* __restrict__ flag, int n,
                                                 int* __restrict__ blockSums,
                                                 unsigned long long* __restrict__ bitmask) {
    __shared__ unsigned long long words[16];       // 1024 bits, consecutive order
    int tid = threadIdx.x;
    int lane = tid & 63, w = tid >> 6;
    if (tid < 16) words[tid] = 0ull;
    __syncthreads();
    int base = blockIdx.x * CHUNK + tid * EPT;
    unsigned nib = 0;
    if (base + EPT <= n) {
        uchar4 f = *reinterpret_cast<const uchar4*>(flag + base);
        nib = (unsigned)f.x | ((unsigned)f.y << 1) | ((unsigned)f.z << 2) | ((unsigned)f.w << 3);
    } else {
        #pragma unroll
        for (int j = 0; j < EPT; ++j)
            if (base + j < n) nib |= (unsigned)flag[base + j] << j;
    }
    if (nib)
        atomicOr(&words[tid >> 4], (unsigned long long)nib << ((tid * 4) & 63));
    int cnt = __popc(nib);
    for (int off = 32; off > 0; off >>= 1)
        cnt += __shfl_down(cnt, off, 64);
    __shared__ int ws[BLOCK / 64];
    if (lane == 0) ws[w] = cnt;
    __syncthreads();                                // atomicOrs + ws complete
    if (tid < 16) bitmask[(size_t)blockIdx.x * 16 + tid] = words[tid];
    if (tid == 0) {
        int s = 0;
        #pragma unroll
        for (int q = 0; q < BLOCK / 64; ++q) s += ws[q];
        blockSums[blockIdx.x] = s;
    }
}

// ---------- F: single-block scan of blockSums ----------
__global__ __launch_bounds__(1024) void k_scan(int* __restrict__ sums, int B) {
    int tid = threadIdx.x;
    int carry = 0;
    for (int b0 = 0; b0 < B; b0 += 1024) {
        int b = b0 + tid;
        int v = (b < B) ? sums[b] : 0;
        int tot;
        int excl = blk_excl_scan<1024>(v, tid, &tot);
        if (b < B) sums[b] = carry + excl;
        carry += tot;
    }
}

// ---------- G: LDS-free per-bucket id assignment (race-free via RANK_BIT) ----------
// A pair claims "first occurrence" iff slice[kl]==pos. The only writer of
// slice[kl] is the unique true-first pair, which writes id|RANK_BIT. Since
// ids|RANK_BIT (>=2^30) are disjoint from positions (<2^22), a concurrent or
// stale read can never false-positive. Output ids are timing-independent.
__global__ __launch_bounds__(512) void k_ids(const unsigned* __restrict__ posArr,
                                             const unsigned short* __restrict__ klArr,
                                             const unsigned* __restrict__ bucketBase,
                                             const int* __restrict__ blockSums,
                                             const unsigned long long* __restrict__ bitmask,
                                             const int* __restrict__ mtp,
                                             int* __restrict__ table) {
    int j = blockIdx.x / IDS_SPLIT, q = blockIdx.x % IDS_SPLIT;
    int tid = threadIdx.x;
    unsigned s0 = bucketBase[j], e0 = bucketBase[j + 1];
    unsigned len = e0 - s0;
    unsigned qlen = (len + IDS_SPLIT - 1) / IDS_SPLIT;
    unsigned s = s0 + q * qlen;
    unsigned e = (s + qlen < e0) ? s + qlen : e0;
    int* slice = table + (size_t)j * KPB;
    int mt = mtp[0];
    for (unsigned idx = s + tid; idx < e; idx += 512) {
        unsigned pos = posArr[idx];
        unsigned kl = klArr[idx];
        if (slice[kl] == (int)pos) {                 // unique true first
            const unsigned long long* bm = bitmask + (size_t)(pos >> 10) * 16;
            unsigned bit = pos & 1023u;
            unsigned w0 = bit >> 6, b0 = bit & 63u;
            int r = blockSums[pos >> 10];
            for (unsigned w = 0; w < w0; ++w) r += __popcll(bm[w]);
            r += __popcll(bm[w0] & ((1ull << b0) - 1ull));
            int id = (r < mt) ? r + 1 : 0;
            slice[kl] = id | RANK_BIT;
        }
    }
}

// ---------- H: gather finalized ids (every key in x has RANK_BIT-set id) ----------
__global__ __launch_bounds__(BLOCK) void k_out(const int* __restrict__ x, int n,
                                               const int* __restrict__ table,
                                               int* __restrict__ out) {
    int base = (blockIdx.x * BLOCK + threadIdx.x) * EPT;
    if (base + EPT <= n) {
        int4 v = *reinterpret_cast<const int4*>(x + base);
        int4 o;
        o.x = table[(unsigned)v.x & TABLE_MASK] & RANK_MASK;
        o.y = table[(unsigned)v.y & TABLE_MASK] & RANK_MASK;
        o.z = table[(unsigned)v.z & TABLE_MASK] & RANK_MASK;
        o.w = table[(unsigned)v.w & TABLE_MASK] & RANK_MASK;
        *reinterpret_cast<int4*>(out + base) = o;
    } else {
        for (int i = base; i < n; ++i)
            out[i] = table[(unsigned)x[i] & TABLE_MASK] & RANK_MASK;
    }
}

// ---------- fallback path (small ws): device-scope atomics ----------
__global__ __launch_bounds__(BLOCK) void k_first_idx(const int* __restrict__ x, int n,
                                                     int* __restrict__ table) {
    int base = (blockIdx.x * BLOCK + threadIdx.x) * EPT;
    for (int i = base; i < min(base + EPT, n); ++i)
        atomicMin(&table[(unsigned)x[i] & TABLE_MASK], i);
}
__global__ __launch_bounds__(BLOCK) void k_count_fb(const int* __restrict__ x, int n,
                                                    const int* __restrict__ table,
                                                    int* __restrict__ blockSums) {
    int tid = threadIdx.x;
    int base = blockIdx.x * CHUNK + tid * EPT;
    int cnt = 0;
    #pragma unroll
    for (int j = 0; j < EPT; ++j)
        if (base + j < n)
            cnt += (table[(unsigned)x[base + j] & TABLE_MASK] == base + j);
    int tot;
    blk_excl_scan<BLOCK>(cnt, tid, &tot);
    if (tid == 0) blockSums[blockIdx.x] = tot;
}
__global__ __launch_bounds__(BLOCK) void k_rank_fb(const int* __restrict__ x, int n,
                                                   int* __restrict__ table,
                                                   const int* __restrict__ blockSums) {
    int tid = threadIdx.x;
    int base = blockIdx.x * CHUNK + tid * EPT;
    int flags[EPT];
    int cnt = 0;
    #pragma unroll
    for (int j = 0; j < EPT; ++j) {
        flags[j] = 0;
        if (base + j < n)
            flags[j] = (table[(unsigned)x[base + j] & TABLE_MASK] == base + j);
        cnt += flags[j];
    }
    int tot;
    int r = blockSums[blockIdx.x] + blk_excl_scan<BLOCK>(cnt, tid, &tot);
    #pragma unroll
    for (int j = 0; j < EPT; ++j)
        if (flags[j]) table[(unsigned)x[base + j] & TABLE_MASK] = (r++) | RANK_BIT;
}
__global__ __launch_bounds__(BLOCK) void k_out_fb(const int* __restrict__ x, int n,
                                                  const int* __restrict__ table,
                                                  const int* __restrict__ mtp,
                                                  int* __restrict__ out) {
    int mt = mtp[0];
    int base = (blockIdx.x * BLOCK + threadIdx.x) * EPT;
    for (int i = base; i < min(base + EPT, n); ++i) {
        int r = table[(unsigned)x[i] & TABLE_MASK] & RANK_MASK;
        out[i] = (r < mt) ? r + 1 : 0;
    }
}

extern "C" void kernel_launch(void* const* d_in, const int* in_sizes, int n_in,
                              void* d_out, int out_size, void* d_ws, size_t ws_size,
                              hipStream_t stream) {
    const int* x   = (const int*)d_in[0];
    const int* mtp = (const int*)d_in[1];
    int n = in_sizes[0];
    int* out = (int*)d_out;

    int SB  = (n + CHUNK  - 1) / CHUNK;    // 1024-granularity blocks
    int SB2 = (n + CHUNK2 - 1) / CHUNK2;   // 4096-granularity blocks

    auto align16 = [](size_t v) { return (v + 15) & ~(size_t)15; };
    size_t off = 0;
    int* table = (int*)d_ws;                                      off = align16(off + (size_t)TABLE_SIZE * 4);
    unsigned* posArr = (unsigned*)((char*)d_ws + off);            off = align16(off + (size_t)n * 4);
    unsigned short* klArr = (unsigned short*)((char*)d_ws + off); off = align16(off + (size_t)n * 2);
    unsigned char* flag = (unsigned char*)((char*)d_ws + off);    off = align16(off + (size_t)n);
    unsigned* hist = (unsigned*)((char*)d_ws + off);              off = align16(off + (size_t)SB2 * NB * 4);
    unsigned* bucketTot = (unsigned*)((char*)d_ws + off);         off = align16(off + (size_t)NB * 4);
    unsigned* bucketBase = (unsigned*)((char*)d_ws + off);        off = align16(off + (size_t)(NB + 1) * 4);
    int* blockSums = (int*)((char*)d_ws + off);                   off = align16(off + (size_t)SB * 4);
    unsigned long long* bitmask = (unsigned long long*)((char*)d_ws + off);
    off = align16(off + (size_t)SB * 16 * 8);

    if (ws_size >= off) {
        k_hist      <<<SB2, BLOCK, 0, stream>>>(x, n, hist);
        k_colscan   <<<NB,  256,   0, stream>>>(hist, SB2, bucketTot);
        k_bucketbase<<<1,   256,   0, stream>>>(bucketTot, bucketBase);
        k_scatter   <<<SB2, BLOCK, 0, stream>>>(x, n, hist, bucketBase, posArr, klArr);
        k_bucket_min<<<NB,  512,   0, stream>>>(posArr, klArr, bucketBase, table, flag);
        k_flags     <<<SB,  BLOCK, 0, stream>>>(flag, n, blockSums, bitmask);
        k_scan      <<<1,   1024,  0, stream>>>(blockSums, SB);
        k_ids       <<<NB * IDS_SPLIT, 512, 0, stream>>>(posArr, klArr, bucketBase,
                                                         blockSums, bitmask, mtp, table);
        k_out       <<<SB,  BLOCK, 0, stream>>>(x, n, table, out);
    } else {
        // minimal-footprint fallback
        size_t foff = align16((size_t)TABLE_SIZE * 4);
        int* bs = (int*)((char*)d_ws + foff);
        hipMemsetAsync(table, 0x7F, (size_t)TABLE_SIZE * 4, stream);
        k_first_idx<<<SB, BLOCK, 0, stream>>>(x, n, table);
        k_count_fb <<<SB, BLOCK, 0, stream>>>(x, n, table, bs);
        k_scan     <<<1, 1024, 0, stream>>>(bs, SB);
        k_rank_fb  <<<SB, BLOCK, 0, stream>>>(x, n, table, bs);
        k_out_fb   <<<SB, BLOCK, 0, stream>>>(x, n, table, mtp, out);
    }
}

// Round 10
// 164.019 us; speedup vs baseline: 1.1249x; 1.1249x over previous
//
#include <hip/hip_runtime.h>
#include <stdint.h>

#define TABLE_BITS 21
#define TABLE_SIZE (1u << TABLE_BITS)      // 2,097,152 entries > max key 1,999,999
#define TABLE_MASK (TABLE_SIZE - 1u)
#define BLOCK 256
#define EPT 4
#define CHUNK (BLOCK * EPT)                // 1024 elements/block (flags/out)
#define EPT2 16
#define CHUNK2 (BLOCK * EPT2)              // 4096 elements/block (hist/scatter)
#define RANK_BIT 0x40000000                // fallback path only
#define RANK_MASK 0x3FFFFFFF
#define NB 256                             // key-range buckets
#define BSHIFT (TABLE_BITS - 8)            // 8192 keys per bucket
#define KPB (1 << BSHIFT)
#define KLOW_MASK (KPB - 1)
#define INF_PAT 0x7f7f7f7f
#define BJ_INVALID 0xFFFFFFFFu

// ---- block exclusive scan (NT threads) ----
template<int NT>
__device__ __forceinline__ int blk_excl_scan(int v, int tid, int* total) {
    constexpr int NW = NT / 64;
    int lane = tid & 63, w = tid >> 6;
    int inc = v;
    #pragma unroll
    for (int off = 1; off < 64; off <<= 1) {
        int u = __shfl_up(inc, off, 64);
        if (lane >= off) inc += u;
    }
    __shared__ int part[NW];
    if (lane == 63) part[w] = inc;
    __syncthreads();
    if (tid < NW) {
        int p = part[tid];
        #pragma unroll
        for (int off = 1; off < NW; off <<= 1) {
            int u = __shfl_up(p, off, 64);
            if (tid >= off) p += u;
        }
        part[tid] = p;
    }
    __syncthreads();
    int excl = ((w == 0) ? 0 : part[w - 1]) + inc - v;
    int tot = part[NW - 1];
    __syncthreads();
    if (total) *total = tot;
    return excl;
}

// ---------- A: per-block 256-bucket histogram (LDS atomics only) ----------
__global__ __launch_bounds__(BLOCK) void k_hist(const int* __restrict__ x, int n,
                                                unsigned* __restrict__ hist) {
    __shared__ unsigned cnt[NB];
    int tid = threadIdx.x;
    cnt[tid] = 0;
    __syncthreads();
    int e0 = blockIdx.x * CHUNK2;
    #pragma unroll
    for (int k = 0; k < EPT2 / 4; ++k) {
        int idx = e0 + k * (BLOCK * 4) + tid * 4;
        if (idx + 4 <= n) {
            int4 v = *reinterpret_cast<const int4*>(x + idx);
            atomicAdd(&cnt[((unsigned)v.x & TABLE_MASK) >> BSHIFT], 1u);
            atomicAdd(&cnt[((unsigned)v.y & TABLE_MASK) >> BSHIFT], 1u);
            atomicAdd(&cnt[((unsigned)v.z & TABLE_MASK) >> BSHIFT], 1u);
            atomicAdd(&cnt[((unsigned)v.w & TABLE_MASK) >> BSHIFT], 1u);
        } else {
            for (int i = idx; i < n; ++i)
                atomicAdd(&cnt[((unsigned)x[i] & TABLE_MASK) >> BSHIFT], 1u);
        }
    }
    __syncthreads();
    hist[(size_t)blockIdx.x * NB + tid] = cnt[tid];
}

// ---------- B: per-bucket exclusive scan over blocks (in place) ----------
__global__ __launch_bounds__(256) void k_colscan(unsigned* __restrict__ hist, int SB2,
                                                 unsigned* __restrict__ bucketTot) {
    int j = blockIdx.x, tid = threadIdx.x;
    unsigned carry = 0;
    for (int b0 = 0; b0 < SB2; b0 += 256) {
        int b = b0 + tid;
        int v = (b < SB2) ? (int)hist[(size_t)b * NB + j] : 0;
        int tot;
        int excl = blk_excl_scan<256>(v, tid, &tot);
        if (b < SB2) hist[(size_t)b * NB + j] = carry + (unsigned)excl;
        carry += (unsigned)tot;
    }
    if (tid == 0) bucketTot[j] = carry;
}

// ---------- C: LDS-staged scatter -> packed 8B pairs grouped by bucket ----------
// bucketBase is derived in-block from bucketTot (saves the k_bucketbase launch).
__global__ __launch_bounds__(BLOCK) void k_scatter(const int* __restrict__ x, int n,
                                                   const unsigned* __restrict__ hist,
                                                   const unsigned* __restrict__ bucketTot,
                                                   unsigned long long* __restrict__ pairs) {
    __shared__ unsigned cnt[NB];
    __shared__ unsigned lbase[NB + 1];
    __shared__ unsigned sbase[NB];
    __shared__ unsigned long long lp[CHUNK2];      // 32 KB staging
    int tid = threadIdx.x;
    cnt[tid] = 0;
    // in-block exclusive scan of bucketTot -> bucketBase
    {
        int v = (int)bucketTot[tid];
        int tot;
        int ex = blk_excl_scan<256>(v, tid, &tot);
        sbase[tid] = (unsigned)ex + hist[(size_t)blockIdx.x * NB + tid];
    }
    __syncthreads();

    unsigned bjs[EPT2], kls[EPT2], los[EPT2];
    int e0 = blockIdx.x * CHUNK2;
    // pass 1: bucket ids + local offsets
    #pragma unroll
    for (int k = 0; k < EPT2 / 4; ++k) {
        int idx = e0 + k * (BLOCK * 4) + tid * 4;
        if (idx + 4 <= n) {
            int4 v = *reinterpret_cast<const int4*>(x + idx);
            unsigned kk[4] = {(unsigned)v.x & TABLE_MASK, (unsigned)v.y & TABLE_MASK,
                              (unsigned)v.z & TABLE_MASK, (unsigned)v.w & TABLE_MASK};
            #pragma unroll
            for (int j = 0; j < 4; ++j) {
                int e = k * 4 + j;
                bjs[e] = kk[j] >> BSHIFT;
                kls[e] = kk[j] & KLOW_MASK;
                los[e] = atomicAdd(&cnt[bjs[e]], 1u);
            }
        } else {
            #pragma unroll
            for (int j = 0; j < 4; ++j) {
                int e = k * 4 + j;
                int i = idx + j;
                if (i < n) {
                    unsigned kv = (unsigned)x[i] & TABLE_MASK;
                    bjs[e] = kv >> BSHIFT;
                    kls[e] = kv & KLOW_MASK;
                    los[e] = atomicAdd(&cnt[bjs[e]], 1u);
                } else {
                    bjs[e] = BJ_INVALID;
                }
            }
        }
    }
    __syncthreads();
    // scan local counts -> local bucket bases
    {
        int v = (int)cnt[tid];
        int tot;
        int ex = blk_excl_scan<256>(v, tid, &tot);
        lbase[tid] = (unsigned)ex;
        if (tid == 255) lbase[256] = (unsigned)(ex + v);
    }
    __syncthreads();
    // pass 2: place pairs into LDS ordered by bucket
    #pragma unroll
    for (int k = 0; k < EPT2 / 4; ++k) {
        #pragma unroll
        for (int j = 0; j < 4; ++j) {
            int e = k * 4 + j;
            if (bjs[e] != BJ_INVALID) {
                unsigned pos = (unsigned)(e0 + k * (BLOCK * 4) + tid * 4 + j);
                lp[lbase[bjs[e]] + los[e]] =
                    ((unsigned long long)kls[e] << 32) | pos;
            }
        }
    }
    __syncthreads();
    // flush: wave per bucket, contiguous bursts
    int wv = tid >> 6, ln = tid & 63;
    for (int j = wv; j < NB; j += BLOCK / 64) {
        unsigned ls = lbase[j], len = lbase[j + 1] - ls, gs = sbase[j];
        for (unsigned i = ln; i < len; i += 64)
            pairs[gs + i] = lp[ls + i];
    }
}

// ---------- D: per-bucket first-idx in LDS; coalesced table write + flag bytes ----------
__global__ __launch_bounds__(512) void k_bucket_min(const unsigned long long* __restrict__ pairs,
                                                    const unsigned* __restrict__ bucketTot,
                                                    const unsigned* __restrict__ hist0,
                                                    int SB2,
                                                    int* __restrict__ table,
                                                    unsigned char* __restrict__ flag) {
    __shared__ int fi[KPB];                 // 32 KB
    __shared__ unsigned sbeg, send;
    int j = blockIdx.x, tid = threadIdx.x;
    for (int k = tid; k < KPB; k += 512) fi[k] = INF_PAT;
    if (tid < 256) {
        // derive bucketBase[j], bucketBase[j+1] from bucketTot via scan
        int v = (int)bucketTot[tid];
        int tot;
        int ex = blk_excl_scan<256>(v, tid, &tot);
        if (tid == j) { sbeg = (unsigned)ex; send = (unsigned)(ex + v); }
    } else {
        int tot; blk_excl_scan<256>(0, tid, &tot);  // keep barriers uniform
    }
    __syncthreads();
    unsigned s = sbeg, e = send;
    for (unsigned idx = s + tid; idx < e; idx += 512) {
        unsigned long long p = pairs[idx];
        atomicMin(&fi[(unsigned)(p >> 32)], (int)(unsigned)p);
    }
    __syncthreads();
    int* dst = table + (size_t)j * KPB;
    for (int k = tid; k < KPB; k += 512) dst[k] = fi[k];
    // flag bytes: every position written exactly once (L2-hot re-read)
    for (unsigned idx = s + tid; idx < e; idx += 512) {
        unsigned long long p = pairs[idx];
        unsigned pos = (unsigned)p;
        flag[pos] = (unsigned char)(fi[(unsigned)(p >> 32)] == (int)pos);
    }
}

// ---------- E: flag bytes -> consecutive-bit per-block bitmask + blockSums ----------
__global__ __launch_bounds__(BLOCK) void k_flags(const unsigned char* __restrict__ flag, int n,
                                                 int* __restrict__ blockSums,
                                                 unsigned long long* __restrict__ bitmask) {
    __shared__ unsigned long long words[16];       // 1024 bits, consecutive order
    int tid = threadIdx.x;
    int lane = tid & 63, w = tid >> 6;
    if (tid < 16) words[tid] = 0ull;
    __syncthreads();
    int base = blockIdx.x * CHUNK + tid * EPT;
    unsigned nib = 0;
    if (base + EPT <= n) {
        uchar4 f = *reinterpret_cast<const uchar4*>(flag + base);
        nib = (unsigned)f.x | ((unsigned)f.y << 1) | ((unsigned)f.z << 2) | ((unsigned)f.w << 3);
    } else {
        #pragma unroll
        for (int j = 0; j < EPT; ++j)
            if (base + j < n) nib |= (unsigned)flag[base + j] << j;
    }
    if (nib)
        atomicOr(&words[tid >> 4], (unsigned long long)nib << ((tid * 4) & 63));
    int cnt = __popc(nib);
    for (int off = 32; off > 0; off >>= 1)
        cnt += __shfl_down(cnt, off, 64);
    __shared__ int ws[BLOCK / 64];
    if (lane == 0) ws[w] = cnt;
    __syncthreads();
    if (tid < 16) bitmask[(size_t)blockIdx.x * 16 + tid] = words[tid];
    if (tid == 0) {
        int s = 0;
        #pragma unroll
        for (int q = 0; q < BLOCK / 64; ++q) s += ws[q];
        blockSums[blockIdx.x] = s;
    }
}

// ---------- F: single-block scan of blockSums ----------
__global__ __launch_bounds__(1024) void k_scan(int* __restrict__ sums, int B) {
    int tid = threadIdx.x;
    int carry = 0;
    for (int b0 = 0; b0 < B; b0 += 1024) {
        int b = b0 + tid;
        int v = (b < B) ? sums[b] : 0;
        int tot;
        int excl = blk_excl_scan<1024>(v, tid, &tot);
        if (b < B) sums[b] = carry + excl;
        carry += tot;
    }
}

// ---------- G: fused gather + on-the-fly rank ----------
// table holds first-indices (never id-rewritten -> no scattered table stores
// anywhere after k_bucket_min's coalesced write). rank(fi) = blockSums[fi>>10]
// + popcount prefix within the 1024-bit block mask (bitmask: 410KB, L2-hot).
__global__ __launch_bounds__(BLOCK) void k_out_fused(const int* __restrict__ x, int n,
                                                     const int* __restrict__ table,
                                                     const int* __restrict__ blockSums,
                                                     const unsigned long long* __restrict__ bitmask,
                                                     const int* __restrict__ mtp,
                                                     int* __restrict__ out) {
    int mt = mtp[0];
    int base = (blockIdx.x * BLOCK + threadIdx.x) * EPT;
    auto rank_of = [&](unsigned key) -> int {
        unsigned fi = (unsigned)table[key];          // first index of this key
        const unsigned long long* bm = bitmask + (size_t)(fi >> 10) * 16;
        unsigned bit = fi & 1023u;
        unsigned w0 = bit >> 6, b0 = bit & 63u;
        int r = blockSums[fi >> 10];
        for (unsigned w = 0; w < w0; ++w) r += __popcll(bm[w]);
        r += __popcll(bm[w0] & ((1ull << b0) - 1ull));
        return r;
    };
    if (base + EPT <= n) {
        int4 v = *reinterpret_cast<const int4*>(x + base);
        int4 o;
        int r;
        r = rank_of((unsigned)v.x & TABLE_MASK); o.x = (r < mt) ? r + 1 : 0;
        r = rank_of((unsigned)v.y & TABLE_MASK); o.y = (r < mt) ? r + 1 : 0;
        r = rank_of((unsigned)v.z & TABLE_MASK); o.z = (r < mt) ? r + 1 : 0;
        r = rank_of((unsigned)v.w & TABLE_MASK); o.w = (r < mt) ? r + 1 : 0;
        *reinterpret_cast<int4*>(out + base) = o;
    } else {
        for (int i = base; i < n; ++i) {
            int r = rank_of((unsigned)x[i] & TABLE_MASK);
            out[i] = (r < mt) ? r + 1 : 0;
        }
    }
}

// ---------- fallback path (small ws): device-scope atomics ----------
__global__ __launch_bounds__(BLOCK) void k_first_idx(const int* __restrict__ x, int n,
                                                     int* __restrict__ table) {
    int base = (blockIdx.x * BLOCK + threadIdx.x) * EPT;
    for (int i = base; i < min(base + EPT, n); ++i)
        atomicMin(&table[(unsigned)x[i] & TABLE_MASK], i);
}
__global__ __launch_bounds__(BLOCK) void k_count_fb(const int* __restrict__ x, int n,
                                                    const int* __restrict__ table,
                                                    int* __restrict__ blockSums) {
    int tid = threadIdx.x;
    int base = blockIdx.x * CHUNK + tid * EPT;
    int cnt = 0;
    #pragma unroll
    for (int j = 0; j < EPT; ++j)
        if (base + j < n)
            cnt += (table[(unsigned)x[base + j] & TABLE_MASK] == base + j);
    int tot;
    blk_excl_scan<BLOCK>(cnt, tid, &tot);
    if (tid == 0) blockSums[blockIdx.x] = tot;
}
__global__ __launch_bounds__(BLOCK) void k_rank_fb(const int* __restrict__ x, int n,
                                                   int* __restrict__ table,
                                                   const int* __restrict__ blockSums) {
    int tid = threadIdx.x;
    int base = blockIdx.x * CHUNK + tid * EPT;
    int flags[EPT];
    int cnt = 0;
    #pragma unroll
    for (int j = 0; j < EPT; ++j) {
        flags[j] = 0;
        if (base + j < n)
            flags[j] = (table[(unsigned)x[base + j] & TABLE_MASK] == base + j);
        cnt += flags[j];
    }
    int tot;
    int r = blockSums[blockIdx.x] + blk_excl_scan<BLOCK>(cnt, tid, &tot);
    #pragma unroll
    for (int j = 0; j < EPT; ++j)
        if (flags[j]) table[(unsigned)x[base + j] & TABLE_MASK] = (r++) | RANK_BIT;
}
__global__ __launch_bounds__(BLOCK) void k_out_fb(const int* __restrict__ x, int n,
                                                  const int* __restrict__ table,
                                                  const int* __restrict__ mtp,
                                                  int* __restrict__ out) {
    int mt = mtp[0];
    int base = (blockIdx.x * BLOCK + threadIdx.x) * EPT;
    for (int i = base; i < min(base + EPT, n); ++i) {
        int r = table[(unsigned)x[i] & TABLE_MASK] & RANK_MASK;
        out[i] = (r < mt) ? r + 1 : 0;
    }
}

extern "C" void kernel_launch(void* const* d_in, const int* in_sizes, int n_in,
                              void* d_out, int out_size, void* d_ws, size_t ws_size,
                              hipStream_t stream) {
    const int* x   = (const int*)d_in[0];
    const int* mtp = (const int*)d_in[1];
    int n = in_sizes[0];
    int* out = (int*)d_out;

    int SB  = (n + CHUNK  - 1) / CHUNK;    // 1024-granularity blocks
    int SB2 = (n + CHUNK2 - 1) / CHUNK2;   // 4096-granularity blocks

    auto align16 = [](size_t v) { return (v + 15) & ~(size_t)15; };
    size_t off = 0;
    int* table = (int*)d_ws;                                      off = align16(off + (size_t)TABLE_SIZE * 4);
    unsigned long long* pairs = (unsigned long long*)((char*)d_ws + off); off = align16(off + (size_t)n * 8);
    unsigned char* flag = (unsigned char*)((char*)d_ws + off);    off = align16(off + (size_t)n);
    unsigned* hist = (unsigned*)((char*)d_ws + off);              off = align16(off + (size_t)SB2 * NB * 4);
    unsigned* bucketTot = (unsigned*)((char*)d_ws + off);         off = align16(off + (size_t)NB * 4);
    int* blockSums = (int*)((char*)d_ws + off);                   off = align16(off + (size_t)SB * 4);
    unsigned long long* bitmask = (unsigned long long*)((char*)d_ws + off);
    off = align16(off + (size_t)SB * 16 * 8);

    if (ws_size >= off) {
        k_hist      <<<SB2, BLOCK, 0, stream>>>(x, n, hist);
        k_colscan   <<<NB,  256,   0, stream>>>(hist, SB2, bucketTot);
        k_scatter   <<<SB2, BLOCK, 0, stream>>>(x, n, hist, bucketTot, pairs);
        k_bucket_min<<<NB,  512,   0, stream>>>(pairs, bucketTot, hist, SB2, table, flag);
        k_flags     <<<SB,  BLOCK, 0, stream>>>(flag, n, blockSums, bitmask);
        k_scan      <<<1,   1024,  0, stream>>>(blockSums, SB);
        k_out_fused <<<SB,  BLOCK, 0, stream>>>(x, n, table, blockSums, bitmask, mtp, out);
    } else {
        // minimal-footprint fallback
        size_t foff = align16((size_t)TABLE_SIZE * 4);
        int* bs = (int*)((char*)d_ws + foff);
        hipMemsetAsync(table, 0x7F, (size_t)TABLE_SIZE * 4, stream);
        k_first_idx<<<SB, BLOCK, 0, stream>>>(x, n, table);
        k_count_fb <<<SB, BLOCK, 0, stream>>>(x, n, table, bs);
        k_scan     <<<1, 1024, 0, stream>>>(bs, SB);
        k_rank_fb  <<<SB, BLOCK, 0, stream>>>(x, n, table, bs);
        k_out_fb   <<<SB, BLOCK, 0, stream>>>(x, n, table, mtp, out);
    }
}

// Round 11
// 118.537 us; speedup vs baseline: 1.5565x; 1.3837x over previous
//
#include <hip/hip_runtime.h>
#include <stdint.h>

#define TABLE_BITS 21
#define TABLE_SIZE (1u << TABLE_BITS)      // 2,097,152 entries > max key 1,999,999
#define TABLE_MASK (TABLE_SIZE - 1u)
#define BLOCK 256
#define EPT 4
#define CHUNK (BLOCK * EPT)                // 1024 elements/block (flags)
#define EPT3 8
#define CHUNK3 (BLOCK * EPT3)              // 2048 elements/block (out)
#define EPT2 16
#define CHUNK2 (BLOCK * EPT2)              // 4096 elements/block (hist/scatter)
#define RANK_BIT 0x40000000                // fallback path only
#define RANK_MASK 0x3FFFFFFF
#define NB 256                             // key-range buckets
#define BSHIFT (TABLE_BITS - 8)            // 8192 keys per bucket
#define KPB (1 << BSHIFT)
#define KLOW_MASK (KPB - 1)
#define INF_PAT 0x7f7f7f7f
#define BJ_INVALID 0xFFFFFFFFu

// ---- block exclusive scan (NT threads) ----
template<int NT>
__device__ __forceinline__ int blk_excl_scan(int v, int tid, int* total) {
    constexpr int NW = NT / 64;
    int lane = tid & 63, w = tid >> 6;
    int inc = v;
    #pragma unroll
    for (int off = 1; off < 64; off <<= 1) {
        int u = __shfl_up(inc, off, 64);
        if (lane >= off) inc += u;
    }
    __shared__ int part[NW];
    if (lane == 63) part[w] = inc;
    __syncthreads();
    if (tid < NW) {
        int p = part[tid];
        #pragma unroll
        for (int off = 1; off < NW; off <<= 1) {
            int u = __shfl_up(p, off, 64);
            if (tid >= off) p += u;
        }
        part[tid] = p;
    }
    __syncthreads();
    int excl = ((w == 0) ? 0 : part[w - 1]) + inc - v;
    int tot = part[NW - 1];
    __syncthreads();
    if (total) *total = tot;
    return excl;
}

// ---------- A: per-block 256-bucket histogram (LDS atomics only) ----------
__global__ __launch_bounds__(BLOCK) void k_hist(const int* __restrict__ x, int n,
                                                unsigned* __restrict__ hist) {
    __shared__ unsigned cnt[NB];
    int tid = threadIdx.x;
    cnt[tid] = 0;
    __syncthreads();
    int e0 = blockIdx.x * CHUNK2;
    #pragma unroll
    for (int k = 0; k < EPT2 / 4; ++k) {
        int idx = e0 + k * (BLOCK * 4) + tid * 4;
        if (idx + 4 <= n) {
            int4 v = *reinterpret_cast<const int4*>(x + idx);
            atomicAdd(&cnt[((unsigned)v.x & TABLE_MASK) >> BSHIFT], 1u);
            atomicAdd(&cnt[((unsigned)v.y & TABLE_MASK) >> BSHIFT], 1u);
            atomicAdd(&cnt[((unsigned)v.z & TABLE_MASK) >> BSHIFT], 1u);
            atomicAdd(&cnt[((unsigned)v.w & TABLE_MASK) >> BSHIFT], 1u);
        } else {
            for (int i = idx; i < n; ++i)
                atomicAdd(&cnt[((unsigned)x[i] & TABLE_MASK) >> BSHIFT], 1u);
        }
    }
    __syncthreads();
    hist[(size_t)blockIdx.x * NB + tid] = cnt[tid];
}

// ---------- B: per-bucket exclusive scan over blocks (in place) ----------
__global__ __launch_bounds__(256) void k_colscan(unsigned* __restrict__ hist, int SB2,
                                                 unsigned* __restrict__ bucketTot) {
    int j = blockIdx.x, tid = threadIdx.x;
    unsigned carry = 0;
    for (int b0 = 0; b0 < SB2; b0 += 256) {
        int b = b0 + tid;
        int v = (b < SB2) ? (int)hist[(size_t)b * NB + j] : 0;
        int tot;
        int excl = blk_excl_scan<256>(v, tid, &tot);
        if (b < SB2) hist[(size_t)b * NB + j] = carry + (unsigned)excl;
        carry += (unsigned)tot;
    }
    if (tid == 0) bucketTot[j] = carry;
}

// ---------- C: LDS-staged scatter -> packed 8B pairs grouped by bucket ----------
__global__ __launch_bounds__(BLOCK) void k_scatter(const int* __restrict__ x, int n,
                                                   const unsigned* __restrict__ hist,
                                                   const unsigned* __restrict__ bucketTot,
                                                   unsigned long long* __restrict__ pairs) {
    __shared__ unsigned cnt[NB];
    __shared__ unsigned lbase[NB + 1];
    __shared__ unsigned sbase[NB];
    __shared__ unsigned long long lp[CHUNK2];      // 32 KB staging
    int tid = threadIdx.x;
    cnt[tid] = 0;
    // in-block exclusive scan of bucketTot -> bucketBase
    {
        int v = (int)bucketTot[tid];
        int tot;
        int ex = blk_excl_scan<256>(v, tid, &tot);
        sbase[tid] = (unsigned)ex + hist[(size_t)blockIdx.x * NB + tid];
    }
    __syncthreads();

    unsigned bjs[EPT2], kls[EPT2], los[EPT2];
    int e0 = blockIdx.x * CHUNK2;
    // pass 1: bucket ids + local offsets
    #pragma unroll
    for (int k = 0; k < EPT2 / 4; ++k) {
        int idx = e0 + k * (BLOCK * 4) + tid * 4;
        if (idx + 4 <= n) {
            int4 v = *reinterpret_cast<const int4*>(x + idx);
            unsigned kk[4] = {(unsigned)v.x & TABLE_MASK, (unsigned)v.y & TABLE_MASK,
                              (unsigned)v.z & TABLE_MASK, (unsigned)v.w & TABLE_MASK};
            #pragma unroll
            for (int j = 0; j < 4; ++j) {
                int e = k * 4 + j;
                bjs[e] = kk[j] >> BSHIFT;
                kls[e] = kk[j] & KLOW_MASK;
                los[e] = atomicAdd(&cnt[bjs[e]], 1u);
            }
        } else {
            #pragma unroll
            for (int j = 0; j < 4; ++j) {
                int e = k * 4 + j;
                int i = idx + j;
                if (i < n) {
                    unsigned kv = (unsigned)x[i] & TABLE_MASK;
                    bjs[e] = kv >> BSHIFT;
                    kls[e] = kv & KLOW_MASK;
                    los[e] = atomicAdd(&cnt[bjs[e]], 1u);
                } else {
                    bjs[e] = BJ_INVALID;
                }
            }
        }
    }
    __syncthreads();
    // scan local counts -> local bucket bases
    {
        int v = (int)cnt[tid];
        int tot;
        int ex = blk_excl_scan<256>(v, tid, &tot);
        lbase[tid] = (unsigned)ex;
        if (tid == 255) lbase[256] = (unsigned)(ex + v);
    }
    __syncthreads();
    // pass 2: place pairs into LDS ordered by bucket
    #pragma unroll
    for (int k = 0; k < EPT2 / 4; ++k) {
        #pragma unroll
        for (int j = 0; j < 4; ++j) {
            int e = k * 4 + j;
            if (bjs[e] != BJ_INVALID) {
                unsigned pos = (unsigned)(e0 + k * (BLOCK * 4) + tid * 4 + j);
                lp[lbase[bjs[e]] + los[e]] =
                    ((unsigned long long)kls[e] << 32) | pos;
            }
        }
    }
    __syncthreads();
    // flush: wave per bucket, contiguous bursts
    int wv = tid >> 6, ln = tid & 63;
    for (int j = wv; j < NB; j += BLOCK / 64) {
        unsigned ls = lbase[j], len = lbase[j + 1] - ls, gs = sbase[j];
        for (unsigned i = ln; i < len; i += 64)
            pairs[gs + i] = lp[ls + i];
    }
}

// ---------- D: per-bucket first-idx in LDS; coalesced table write + flag bytes ----------
__global__ __launch_bounds__(512) void k_bucket_min(const unsigned long long* __restrict__ pairs,
                                                    const unsigned* __restrict__ bucketTot,
                                                    int* __restrict__ table,
                                                    unsigned char* __restrict__ flag) {
    __shared__ int fi[KPB];                 // 32 KB
    __shared__ unsigned sbeg, send;
    int j = blockIdx.x, tid = threadIdx.x;
    for (int k = tid; k < KPB; k += 512) fi[k] = INF_PAT;
    if (tid < 256) {
        int v = (int)bucketTot[tid];
        int tot;
        int ex = blk_excl_scan<256>(v, tid, &tot);
        if (tid == j) { sbeg = (unsigned)ex; send = (unsigned)(ex + v); }
    } else {
        int tot; blk_excl_scan<256>(0, tid, &tot);  // keep barriers uniform
    }
    __syncthreads();
    unsigned s = sbeg, e = send;
    for (unsigned idx = s + tid; idx < e; idx += 512) {
        unsigned long long p = pairs[idx];
        atomicMin(&fi[(unsigned)(p >> 32)], (int)(unsigned)p);
    }
    __syncthreads();
    int* dst = table + (size_t)j * KPB;
    for (int k = tid; k < KPB; k += 512) dst[k] = fi[k];
    // flag bytes: every position written exactly once (L2-hot re-read)
    for (unsigned idx = s + tid; idx < e; idx += 512) {
        unsigned long long p = pairs[idx];
        unsigned pos = (unsigned)p;
        flag[pos] = (unsigned char)(fi[(unsigned)(p >> 32)] == (int)pos);
    }
}

// ---------- E: flag bytes -> consecutive-bit per-block bitmask + blockSums ----------
__global__ __launch_bounds__(BLOCK) void k_flags(const unsigned char* __restrict__ flag, int n,
                                                 int* __restrict__ blockSums,
                                                 unsigned long long* __restrict__ bitmask) {
    __shared__ unsigned long long words[16];       // 1024 bits, consecutive order
    int tid = threadIdx.x;
    int lane = tid & 63, w = tid >> 6;
    if (tid < 16) words[tid] = 0ull;
    __syncthreads();
    int base = blockIdx.x * CHUNK + tid * EPT;
    unsigned nib = 0;
    if (base + EPT <= n) {
        uchar4 f = *reinterpret_cast<const uchar4*>(flag + base);
        nib = (unsigned)f.x | ((unsigned)f.y << 1) | ((unsigned)f.z << 2) | ((unsigned)f.w << 3);
    } else {
        #pragma unroll
        for (int j = 0; j < EPT; ++j)
            if (base + j < n) nib |= (unsigned)flag[base + j] << j;
    }
    if (nib)
        atomicOr(&words[tid >> 4], (unsigned long long)nib << ((tid * 4) & 63));
    int cnt = __popc(nib);
    for (int off = 32; off > 0; off >>= 1)
        cnt += __shfl_down(cnt, off, 64);
    __shared__ int ws[BLOCK / 64];
    if (lane == 0) ws[w] = cnt;
    __syncthreads();
    if (tid < 16) bitmask[(size_t)blockIdx.x * 16 + tid] = words[tid];
    if (tid == 0) {
        int s = 0;
        #pragma unroll
        for (int q = 0; q < BLOCK / 64; ++q) s += ws[q];
        blockSums[blockIdx.x] = s;
    }
}

// ---------- F: single-block scan of blockSums ----------
__global__ __launch_bounds__(1024) void k_scan(int* __restrict__ sums, int B) {
    int tid = threadIdx.x;
    int carry = 0;
    for (int b0 = 0; b0 < B; b0 += 1024) {
        int b = b0 + tid;
        int v = (b < B) ? sums[b] : 0;
        int tot;
        int excl = blk_excl_scan<1024>(v, tid, &tot);
        if (b < B) sums[b] = carry + excl;
        carry += tot;
    }
}

// ---------- F2: word-level absolute prefix sums (one thread per 1024-block) ----------
__global__ __launch_bounds__(256) void k_wordsums(const int* __restrict__ blockSums,
                                                  const unsigned long long* __restrict__ bitmask,
                                                  int B,
                                                  unsigned* __restrict__ wordSums) {
    int b = blockIdx.x * 256 + threadIdx.x;
    if (b >= B) return;
    int r = blockSums[b];
    const unsigned long long* bm = bitmask + (size_t)b * 16;
    unsigned* ws = wordSums + (size_t)b * 16;
    #pragma unroll
    for (int w = 0; w < 16; ++w) {
        ws[w] = (unsigned)r;
        r += __popcll(bm[w]);
    }
}

// ---------- G: fused gather + O(1) rank (wordSums + single-word popcount) ----------
__global__ __launch_bounds__(BLOCK) void k_out_fused(const int* __restrict__ x, int n,
                                                     const int* __restrict__ table,
                                                     const unsigned* __restrict__ wordSums,
                                                     const unsigned long long* __restrict__ bitmask,
                                                     const int* __restrict__ mtp,
                                                     int* __restrict__ out) {
    int mt = mtp[0];
    int base = blockIdx.x * CHUNK3 + threadIdx.x * 4;
    auto rank_of = [&](unsigned key) -> int {
        unsigned fi = (unsigned)table[key];          // first index of this key
        unsigned wi = fi >> 6;
        // two independent L2-hot loads (205KB + 410KB working sets)
        int r = (int)wordSums[wi];
        r += __popcll(bitmask[wi] & ((1ull << (fi & 63u)) - 1ull));
        return r;
    };
    #pragma unroll
    for (int k = 0; k < EPT3 / 4; ++k) {
        int idx = base + k * (BLOCK * 4);
        if (idx + 4 <= n) {
            int4 v = *reinterpret_cast<const int4*>(x + idx);
            int4 o;
            int r;
            r = rank_of((unsigned)v.x & TABLE_MASK); o.x = (r < mt) ? r + 1 : 0;
            r = rank_of((unsigned)v.y & TABLE_MASK); o.y = (r < mt) ? r + 1 : 0;
            r = rank_of((unsigned)v.z & TABLE_MASK); o.z = (r < mt) ? r + 1 : 0;
            r = rank_of((unsigned)v.w & TABLE_MASK); o.w = (r < mt) ? r + 1 : 0;
            *reinterpret_cast<int4*>(out + idx) = o;
        } else {
            for (int i = idx; i < n; ++i) {
                int r = rank_of((unsigned)x[i] & TABLE_MASK);
                out[i] = (r < mt) ? r + 1 : 0;
            }
        }
    }
}

// ---------- fallback path (small ws): device-scope atomics ----------
__global__ __launch_bounds__(BLOCK) void k_first_idx(const int* __restrict__ x, int n,
                                                     int* __restrict__ table) {
    int base = (blockIdx.x * BLOCK + threadIdx.x) * EPT;
    for (int i = base; i < min(base + EPT, n); ++i)
        atomicMin(&table[(unsigned)x[i] & TABLE_MASK], i);
}
__global__ __launch_bounds__(BLOCK) void k_count_fb(const int* __restrict__ x, int n,
                                                    const int* __restrict__ table,
                                                    int* __restrict__ blockSums) {
    int tid = threadIdx.x;
    int base = blockIdx.x * CHUNK + tid * EPT;
    int cnt = 0;
    #pragma unroll
    for (int j = 0; j < EPT; ++j)
        if (base + j < n)
            cnt += (table[(unsigned)x[base + j] & TABLE_MASK] == base + j);
    int tot;
    blk_excl_scan<BLOCK>(cnt, tid, &tot);
    if (tid == 0) blockSums[blockIdx.x] = tot;
}
__global__ __launch_bounds__(BLOCK) void k_rank_fb(const int* __restrict__ x, int n,
                                                   int* __restrict__ table,
                                                   const int* __restrict__ blockSums) {
    int tid = threadIdx.x;
    int base = blockIdx.x * CHUNK + tid * EPT;
    int flags[EPT];
    int cnt = 0;
    #pragma unroll
    for (int j = 0; j < EPT; ++j) {
        flags[j] = 0;
        if (base + j < n)
            flags[j] = (table[(unsigned)x[base + j] & TABLE_MASK] == base + j);
        cnt += flags[j];
    }
    int tot;
    int r = blockSums[blockIdx.x] + blk_excl_scan<BLOCK>(cnt, tid, &tot);
    #pragma unroll
    for (int j = 0; j < EPT; ++j)
        if (flags[j]) table[(unsigned)x[base + j] & TABLE_MASK] = (r++) | RANK_BIT;
}
__global__ __launch_bounds__(BLOCK) void k_out_fb(const int* __restrict__ x, int n,
                                                  const int* __restrict__ table,
                                                  const int* __restrict__ mtp,
                                                  int* __restrict__ out) {
    int mt = mtp[0];
    int base = (blockIdx.x * BLOCK + threadIdx.x) * EPT;
    for (int i = base; i < min(base + EPT, n); ++i) {
        int r = table[(unsigned)x[i] & TABLE_MASK] & RANK_MASK;
        out[i] = (r < mt) ? r + 1 : 0;
    }
}

extern "C" void kernel_launch(void* const* d_in, const int* in_sizes, int n_in,
                              void* d_out, int out_size, void* d_ws, size_t ws_size,
                              hipStream_t stream) {
    const int* x   = (const int*)d_in[0];
    const int* mtp = (const int*)d_in[1];
    int n = in_sizes[0];
    int* out = (int*)d_out;

    int SB  = (n + CHUNK  - 1) / CHUNK;    // 1024-granularity blocks
    int SB2 = (n + CHUNK2 - 1) / CHUNK2;   // 4096-granularity blocks
    int SB3 = (n + CHUNK3 - 1) / CHUNK3;   // 2048-granularity blocks

    auto align16 = [](size_t v) { return (v + 15) & ~(size_t)15; };
    size_t off = 0;
    int* table = (int*)d_ws;                                      off = align16(off + (size_t)TABLE_SIZE * 4);
    unsigned long long* pairs = (unsigned long long*)((char*)d_ws + off); off = align16(off + (size_t)n * 8);
    unsigned char* flag = (unsigned char*)((char*)d_ws + off);    off = align16(off + (size_t)n);
    unsigned* hist = (unsigned*)((char*)d_ws + off);              off = align16(off + (size_t)SB2 * NB * 4);
    unsigned* bucketTot = (unsigned*)((char*)d_ws + off);         off = align16(off + (size_t)NB * 4);
    int* blockSums = (int*)((char*)d_ws + off);                   off = align16(off + (size_t)SB * 4);
    unsigned long long* bitmask = (unsigned long long*)((char*)d_ws + off);
    off = align16(off + (size_t)SB * 16 * 8);
    unsigned* wordSums = (unsigned*)((char*)d_ws + off);          off = align16(off + (size_t)SB * 16 * 4);

    if (ws_size >= off) {
        k_hist      <<<SB2, BLOCK, 0, stream>>>(x, n, hist);
        k_colscan   <<<NB,  256,   0, stream>>>(hist, SB2, bucketTot);
        k_scatter   <<<SB2, BLOCK, 0, stream>>>(x, n, hist, bucketTot, pairs);
        k_bucket_min<<<NB,  512,   0, stream>>>(pairs, bucketTot, table, flag);
        k_flags     <<<SB,  BLOCK, 0, stream>>>(flag, n, blockSums, bitmask);
        k_scan      <<<1,   1024,  0, stream>>>(blockSums, SB);
        k_wordsums  <<<(SB + 255) / 256, 256, 0, stream>>>(blockSums, bitmask, SB, wordSums);
        k_out_fused <<<SB3, BLOCK, 0, stream>>>(x, n, table, wordSums, bitmask, mtp, out);
    } else {
        // minimal-footprint fallback
        size_t foff = align16((size_t)TABLE_SIZE * 4);
        int* bs = (int*)((char*)d_ws + foff);
        hipMemsetAsync(table, 0x7F, (size_t)TABLE_SIZE * 4, stream);
        k_first_idx<<<SB, BLOCK, 0, stream>>>(x, n, table);
        k_count_fb <<<SB, BLOCK, 0, stream>>>(x, n, table, bs);
        k_scan     <<<1, 1024, 0, stream>>>(bs, SB);
        k_rank_fb  <<<SB, BLOCK, 0, stream>>>(x, n, table, bs);
        k_out_fb   <<<SB, BLOCK, 0, stream>>>(x, n, table, mtp, out);
    }
}